// Round 9
// baseline (161.323 us; speedup 1.0000x reference)
//
#include <hip/hip_runtime.h>
#include <hip/hip_bf16.h>

typedef __bf16 bf16x8 __attribute__((ext_vector_type(8)));
typedef __bf16 bf16x4 __attribute__((ext_vector_type(4)));
typedef float  f32x4  __attribute__((ext_vector_type(4)));

#define B_  8
#define T_  2048
#define D_  1024
#define HS_ 64

// ---------------------------------------------------------------------------
// fp32 inputs/outputs; bf16 MFMA internally.
// pack_w -> qkv_fused (M=32/wave register blocking, K-split waves, LDS reduce)
//        -> attn_partial (S^T scheme, register-resident P) -> attn_merge.
//
// Round-8 lesson: qkv's invariant ~42us == per-CU Wp traffic (16 waves x
// 96KB through a thrashing 32KB L1 = 1536 missing loads x ~65cyc). Fix is
// reuse, not scheduling: M=32 rows/wave halves waves/CU and doubles
// MFMAs per loaded Wp fragment.
// ---------------------------------------------------------------------------

// Kernel 0: pack the three [D,HS] fp32 weights into bf16 MFMA-fragment order.
__global__ __launch_bounds__(256) void pack_w(
    const float* __restrict__ Wq, const float* __restrict__ Wk,
    const float* __restrict__ Wv, __bf16* __restrict__ Wp)
{
    const int t    = blockIdx.x * 256 + threadIdx.x;   // 0..24575
    const int lane = t & 63;
    const int pg   = t >> 6;                           // 0..383
    const int s    = pg & 3;
    const int c    = (pg >> 2) & 31;
    const int p    = pg >> 7;
    const int m16  = lane & 15;
    const int quad = lane >> 4;

    const float* W = (p == 0) ? Wq : (p == 1) ? Wk : Wv;
    const float* src = W + (size_t)(c * 32 + quad * 8) * 64 + s * 16 + m16;
    bf16x8 frag;
    #pragma unroll
    for (int j = 0; j < 8; ++j) frag[j] = (__bf16)src[(size_t)j * 64];
    *(bf16x8*)(Wp + (size_t)pg * 512 + lane * 8) = frag;
}

// Kernel 1: fused QKV projection, M=32 rows/wave, K-split across waves.
// grid = 512 blocks (32 rows each), block = 256 = 4 waves (2 blocks/CU).
// Phase 1: wave stages its 32x256 x-slice fp32->bf16 into LDS (coalesced).
// Phase 2: 8 k-steps: 2 ds_read_b128 A-frags + 12 contiguous 1KB Wp loads
//          + 24 MFMAs (each Wp fragment reused for both row groups).
// Phase 3: cross-wave reduce through Red (overlays dead Xs) + epilogue.
__global__ __launch_bounds__(256) void qkv_fused(
    const float* __restrict__ x,     // [16384][1024] fp32
    const __bf16* __restrict__ Wp,   // [384][512] fragment-packed bf16
    const float* __restrict__ bq, const float* __restrict__ bk,
    const float* __restrict__ bv,
    __bf16* __restrict__ Q, __bf16* __restrict__ K, __bf16* __restrict__ Vt)
{
    __shared__ alignas(16) unsigned char Smem[73728]; // Xs 4x16896 ∪ Red 73728

    const int rt   = blockIdx.x;                  // 0..511
    const int wave = threadIdx.x >> 6;            // K-slice owner
    const int lane = threadIdx.x & 63;
    const int m16  = lane & 15;
    const int quad = lane >> 4;
    const int row0 = rt * 32;

    __bf16* Xs = (__bf16*)(Smem + wave * 16896);  // 32 rows x 264 (pad 8)

    // ---- Phase 1: stage x-slice (32 rows x 256 cols), fp32 -> bf16 ----
    {
        const float* xsrc = x + (size_t)row0 * 1024 + wave * 256;
        const int sr = lane >> 5;                 // 0..1
        const int sc = (lane & 31) * 8;           // 0..248
        #pragma unroll
        for (int i = 0; i < 16; ++i) {
            const int r = i * 2 + sr;
            f32x4 v0 = *(const f32x4*)(xsrc + (size_t)r * 1024 + sc);
            f32x4 v1 = *(const f32x4*)(xsrc + (size_t)r * 1024 + sc + 4);
            bf16x8 w;
            #pragma unroll
            for (int e = 0; e < 4; ++e) { w[e] = (__bf16)v0[e]; w[4 + e] = (__bf16)v1[e]; }
            *(bf16x8*)&Xs[r * 264 + sc] = w;
        }
    }
    __builtin_amdgcn_wave_barrier();   // pin DS write->read order (wave-local)

    // ---- Phase 2: K-loop, 2 row-groups share each Wp fragment ----
    f32x4 acc[3][4][2];
    #pragma unroll
    for (int p = 0; p < 3; ++p)
        #pragma unroll
        for (int s = 0; s < 4; ++s)
            #pragma unroll
            for (int mg = 0; mg < 2; ++mg) acc[p][s][mg] = {0.f, 0.f, 0.f, 0.f};

    for (int k0 = 0; k0 < 256; k0 += 32) {
        bf16x8 a0 = *(const bf16x8*)&Xs[m16 * 264 + k0 + quad * 8];
        bf16x8 a1 = *(const bf16x8*)&Xs[(16 + m16) * 264 + k0 + quad * 8];
        const int cbase = wave * 8 + (k0 >> 5);
        #pragma unroll
        for (int p = 0; p < 3; ++p)
            #pragma unroll
            for (int s = 0; s < 4; ++s) {
                bf16x8 bfrag = *(const bf16x8*)(Wp +
                    ((size_t)((p * 32 + cbase) * 4 + s) << 9) + lane * 8);
                acc[p][s][0] = __builtin_amdgcn_mfma_f32_16x16x32_bf16(a0, bfrag, acc[p][s][0], 0, 0, 0);
                acc[p][s][1] = __builtin_amdgcn_mfma_f32_16x16x32_bf16(a1, bfrag, acc[p][s][1], 0, 0, 0);
            }
    }

    // ---- Phase 3: cross-wave reduce (Red overlays dead Xs) + epilogue ----
    f32x4* Red = (f32x4*)Smem;                    // [3 waves][24][64]
    __syncthreads();                              // all Xs reads done
    if (wave != 0) {
        #pragma unroll
        for (int p = 0; p < 3; ++p)
            #pragma unroll
            for (int s = 0; s < 4; ++s)
                #pragma unroll
                for (int mg = 0; mg < 2; ++mg)
                    Red[((wave - 1) * 24 + (p * 4 + s) * 2 + mg) * 64 + lane] = acc[p][s][mg];
    }
    __syncthreads();
    if (wave != 0) return;

    #pragma unroll
    for (int p = 0; p < 3; ++p)
        #pragma unroll
        for (int s = 0; s < 4; ++s)
            #pragma unroll
            for (int mg = 0; mg < 2; ++mg) {
                f32x4 sum = acc[p][s][mg];
                #pragma unroll
                for (int w = 0; w < 3; ++w) {
                    f32x4 v = Red[(w * 24 + (p * 4 + s) * 2 + mg) * 64 + lane];
                    #pragma unroll
                    for (int e = 0; e < 4; ++e) sum[e] += v[e];
                }
                acc[p][s][mg] = sum;
            }

    // Q epilogue (p=0)
    #pragma unroll
    for (int mg = 0; mg < 2; ++mg)
        #pragma unroll
        for (int s = 0; s < 4; ++s) {
            const int h = s * 16 + m16;
            const float bia = bq[h];
            #pragma unroll
            for (int r = 0; r < 4; ++r)
                Q[(size_t)(row0 + mg * 16 + quad * 4 + r) * 64 + h] = (__bf16)(acc[0][s][mg][r] + bia);
        }
    // K epilogue (p=1)
    #pragma unroll
    for (int mg = 0; mg < 2; ++mg)
        #pragma unroll
        for (int s = 0; s < 4; ++s) {
            const int h = s * 16 + m16;
            const float bia = bk[h];
            #pragma unroll
            for (int r = 0; r < 4; ++r)
                K[(size_t)(row0 + mg * 16 + quad * 4 + r) * 64 + h] = (__bf16)(acc[1][s][mg][r] + bia);
        }
    // V epilogue (p=2), transposed Vt[b][h][t]; 32-row tiles never cross batch
    {
        const int bidx = row0 >> 11;
        #pragma unroll
        for (int mg = 0; mg < 2; ++mg) {
            const int t0 = ((row0 + mg * 16) & 2047) + quad * 4;
            #pragma unroll
            for (int s = 0; s < 4; ++s) {
                const int h = s * 16 + m16;
                const float bia = bv[h];
                bf16x4 pack;
                #pragma unroll
                for (int r = 0; r < 4; ++r) pack[r] = (__bf16)(acc[2][s][mg][r] + bia);
                *(bf16x4*)(Vt + (size_t)bidx * (HS_ * T_) + (size_t)h * T_ + t0) = pack;
            }
        }
    }
}

// Kernel 2: split-K causal attention partials, S^T scheme.
// grid = (8 key-slots, 32 q-tiles, 8 batches), block = 256 (4 waves x 16 q).
__global__ __launch_bounds__(256) void attn_partial(
    const __bf16* __restrict__ Q,   // [8][2048][64]
    const __bf16* __restrict__ K,   // [8][2048][64]
    const __bf16* __restrict__ Vt,  // [8][64][2048]
    float* __restrict__ Opart,      // [8*32*8][64][64]
    float* __restrict__ Ml)         // [8*32*8][64][2]
{
    __shared__ alignas(16) __bf16 Klds[8 * 512];   // 8 frag-groups x 1KB
    __shared__ alignas(16) __bf16 Vlds[8 * 512];

    const int z  = blockIdx.x;      // key slot 0..7
    const int qt = blockIdx.y;      // q tile 0..31
    const int b  = blockIdx.z;      // batch
    if (z > qt) return;             // uniform exit, before any barrier

    const int tid  = threadIdx.x;
    const int wave = tid >> 6;
    const int lane = tid & 63;
    const int m16  = lane & 15;
    const int quad = lane >> 4;

    const __bf16* Qb = Q  + (size_t)b * T_ * HS_;
    const __bf16* Kb = K  + (size_t)b * T_ * HS_;
    const __bf16* Vb = Vt + (size_t)b * HS_ * T_;

    const int q0   = qt * 64 + wave * 16;
    const int qrow = q0 + m16;                    // this lane's q row

    bf16x8 qb0 = *(const bf16x8*)(Qb + (size_t)qrow * 64 + quad * 8);
    bf16x8 qb1 = *(const bf16x8*)(Qb + (size_t)qrow * 64 + 32 + quad * 8);

    f32x4 o[4];                                   // O^T: h=hs*16+quad*4+r, q=m16
    #pragma unroll
    for (int hs = 0; hs < 4; ++hs) o[hs] = {0.f, 0.f, 0.f, 0.f};
    float m_run = -1e30f, l_run = 0.f;

    for (int jt = z; jt <= qt; jt += 8) {         // uniform trip count in block
        const int j0 = jt * 64;

        // stage K,V tile frag-packed; coalesced 16B/thread x2
        #pragma unroll
        for (int i = 0; i < 2; ++i) {
            const int p    = i * 256 + tid;       // piece 0..511
            const int trow = p >> 3;              // 0..63
            const int tcol = p & 7;               // 8-elem chunk
            bf16x8 kv = *(const bf16x8*)(Kb + (size_t)(j0 + trow) * 64 + tcol * 8);
            const int snb = ((trow >> 5) << 1) | ((trow >> 2) & 1);
            const int mk  = (((trow >> 3) & 3) << 2) | (trow & 3);
            *(bf16x8*)&Klds[((((snb << 1) | (tcol >> 2)) << 6) + (tcol & 3) * 16 + mk) * 8] = kv;
            bf16x8 vv = *(const bf16x8*)(Vb + (size_t)trow * T_ + j0 + tcol * 8);
            *(bf16x8*)&Vlds[(((((trow >> 4) << 1) | (tcol >> 2)) << 6) + (tcol & 3) * 16 + (trow & 15)) * 8] = vv;
        }
        __syncthreads();

        // S^T = K.Q^T
        f32x4 s[4];
        #pragma unroll
        for (int snb = 0; snb < 4; ++snb) s[snb] = {0.f, 0.f, 0.f, 0.f};
        #pragma unroll
        for (int snb = 0; snb < 4; ++snb) {
            bf16x8 ka0 = *(const bf16x8*)&Klds[((snb * 2 + 0) * 64 + lane) * 8];
            bf16x8 ka1 = *(const bf16x8*)&Klds[((snb * 2 + 1) * 64 + lane) * 8];
            s[snb] = __builtin_amdgcn_mfma_f32_16x16x32_bf16(ka0, qb0, s[snb], 0, 0, 0);
            s[snb] = __builtin_amdgcn_mfma_f32_16x16x32_bf16(ka1, qb1, s[snb], 0, 0, 0);
        }

        // softmax: lane holds 16 keys of q=qrow; 2+2 shuffles total
        float mx = -1e30f;
        #pragma unroll
        for (int snb = 0; snb < 4; ++snb) {
            const int kbase = j0 + ((snb >> 1) << 5) + (quad << 3) + ((snb & 1) << 2);
            #pragma unroll
            for (int r = 0; r < 4; ++r) {
                float v = s[snb][r] * 0.125f;             // 1/sqrt(64)
                v = (kbase + r <= qrow) ? v : -1e30f;     // causal (phys key)
                s[snb][r] = v;
                mx = fmaxf(mx, v);
            }
        }
        mx = fmaxf(mx, __shfl_xor(mx, 16));
        mx = fmaxf(mx, __shfl_xor(mx, 32));

        const float newm  = fmaxf(m_run, mx);
        const float alpha = __expf(m_run - newm);
        m_run = newm;

        float rs = 0.f;
        #pragma unroll
        for (int snb = 0; snb < 4; ++snb)
            #pragma unroll
            for (int r = 0; r < 4; ++r) {
                float pv = __expf(s[snb][r] - newm);
                s[snb][r] = pv;
                rs += pv;
            }
        rs += __shfl_xor(rs, 16);
        rs += __shfl_xor(rs, 32);
        l_run = l_run * alpha + rs;

        #pragma unroll
        for (int hs = 0; hs < 4; ++hs)
            #pragma unroll
            for (int r = 0; r < 4; ++r) o[hs][r] *= alpha;

        // P^T (registers) -> PV B-operand directly
        bf16x8 pb0, pb1;
        #pragma unroll
        for (int r = 0; r < 4; ++r) {
            pb0[r]     = (__bf16)s[0][r];
            pb0[4 + r] = (__bf16)s[1][r];
            pb1[r]     = (__bf16)s[2][r];
            pb1[4 + r] = (__bf16)s[3][r];
        }

        // O^T += Vt . P^T
        #pragma unroll
        for (int hs = 0; hs < 4; ++hs) {
            bf16x8 va0 = *(const bf16x8*)&Vlds[((hs * 2 + 0) * 64 + lane) * 8];
            bf16x8 va1 = *(const bf16x8*)&Vlds[((hs * 2 + 1) * 64 + lane) * 8];
            o[hs] = __builtin_amdgcn_mfma_f32_16x16x32_bf16(va0, pb0, o[hs], 0, 0, 0);
            o[hs] = __builtin_amdgcn_mfma_f32_16x16x32_bf16(va1, pb1, o[hs], 0, 0, 0);
        }
        __syncthreads();   // LDS reads done before next tile's staging
    }

    // epilogue: Opart[q][h] fp32 (16B stores), Ml per q
    const int slot = (b * 32 + qt) * 8 + z;
    float* Op = Opart + (size_t)slot * 4096;
    #pragma unroll
    for (int hs = 0; hs < 4; ++hs)
        *(f32x4*)(Op + (size_t)(wave * 16 + m16) * 64 + hs * 16 + quad * 4) = o[hs];
    if (quad == 0) {
        Ml[(size_t)slot * 128 + (wave * 16 + m16) * 2 + 0] = m_run;
        Ml[(size_t)slot * 128 + (wave * 16 + m16) * 2 + 1] = l_run;
    }
}

// Kernel 3: merge the <=8 slot-partials per q-tile (log-sum-exp weighting).
__global__ __launch_bounds__(256) void attn_merge(
    const float* __restrict__ Opart, const float* __restrict__ Ml,
    float* __restrict__ O)
{
    const int qt = blockIdx.x;
    const int b  = blockIdx.y;
    const int tid = threadIdx.x;
    const int row = tid >> 2;
    const int colblk = tid & 3;
    const int nc = (qt + 1 < 8) ? qt + 1 : 8;
    const int slotBase = (b * 32 + qt) * 8;

    f32x4 acc[4];
    #pragma unroll
    for (int j = 0; j < 4; ++j) acc[j] = {0.f, 0.f, 0.f, 0.f};
    float M = -1e30f, den = 0.f;

    for (int c = 0; c < nc; ++c) {
        const float* mlp = Ml + (size_t)(slotBase + c) * 128 + row * 2;
        const float mc = mlp[0];
        const float lc = mlp[1];
        const float newM  = fmaxf(M, mc);
        const float alpha = __expf(M - newM);
        const float w     = __expf(mc - newM);
        M = newM;

        const float* op = Opart + (size_t)(slotBase + c) * 4096 + row * 64 + colblk * 16;
        #pragma unroll
        for (int j = 0; j < 4; ++j) {
            f32x4 v = *(const f32x4*)(op + j * 4);
            #pragma unroll
            for (int e = 0; e < 4; ++e) acc[j][e] = acc[j][e] * alpha + w * v[e];
        }
        den = den * alpha + w * lc;
    }

    const float inv = 1.f / den;
    float* out = O + ((size_t)b * T_ + qt * 64 + row) * 64 + colblk * 16;
    #pragma unroll
    for (int j = 0; j < 4; ++j) {
        f32x4 v;
        #pragma unroll
        for (int e = 0; e < 4; ++e) v[e] = acc[j][e] * inv;
        *(f32x4*)(out + j * 4) = v;
    }
}

// ---------------------------------------------------------------------------
extern "C" void kernel_launch(void* const* d_in, const int* in_sizes, int n_in,
                              void* d_out, int out_size, void* d_ws, size_t ws_size,
                              hipStream_t stream)
{
    const float* x  = (const float*)d_in[0];
    const float* Wq = (const float*)d_in[1];
    const float* bq = (const float*)d_in[2];
    const float* Wk = (const float*)d_in[3];
    const float* bk = (const float*)d_in[4];
    const float* Wv = (const float*)d_in[5];
    const float* bv = (const float*)d_in[6];
    float* out = (float*)d_out;

    __bf16* Wp = (__bf16*)d_ws;              // 384*512 bf16         = 0.4 MB
    __bf16* Q  = Wp + 384 * 512;             // 8*2048*64 bf16       = 2 MB
    __bf16* K  = Q  + (size_t)B_ * T_ * HS_;
    __bf16* Vt = K  + (size_t)B_ * T_ * HS_; // transposed [b][h][t]
    float* Opart = (float*)(Vt + (size_t)B_ * T_ * HS_);  // 2048*4096 f32 = 33.6 MB
    float* Ml    = Opart + (size_t)2048 * 4096;           // 2048*128  f32 =  1 MB

    pack_w<<<96, 256, 0, stream>>>(Wq, Wk, Wv, Wp);
    qkv_fused<<<512, 256, 0, stream>>>(x, Wp, bq, bk, bv, Q, K, Vt);
    attn_partial<<<dim3(8, 32, 8), 256, 0, stream>>>(Q, K, Vt, Opart, Ml);
    attn_merge<<<dim3(32, 8), 256, 0, stream>>>(Opart, Ml, out);
}

// Round 10
// 148.815 us; speedup vs baseline: 1.0840x; 1.0840x over previous
//
#include <hip/hip_runtime.h>
#include <hip/hip_bf16.h>

typedef __bf16 bf16x8 __attribute__((ext_vector_type(8)));
typedef __bf16 bf16x4 __attribute__((ext_vector_type(4)));
typedef float  f32x4  __attribute__((ext_vector_type(4)));

#define B_  8
#define T_  2048
#define D_  1024
#define HS_ 64

// ---------------------------------------------------------------------------
// fp32 inputs/outputs; bf16 MFMA internally.
// pack_w -> qkv_fused (M=16/wave, K-split waves, BATCHED Wp loads)
//        -> attn_partial (S^T scheme, register-resident P) -> attn_merge.
//
// Round-9 lesson (r8 vs r9 controlled exp): qkv time does NOT scale with Wp
// bytes; it fits serialized dependent loads at ~1000cyc L2-miss latency
// (12.5k cyc/kstep = 12 x load->waitcnt->mfma pairs). Fix: batch the 12
// loads into registers (MLP 1 -> 12), sched_barrier between batches.
// ---------------------------------------------------------------------------

// Kernel 0: pack the three [D,HS] fp32 weights into bf16 MFMA-fragment order.
__global__ __launch_bounds__(256) void pack_w(
    const float* __restrict__ Wq, const float* __restrict__ Wk,
    const float* __restrict__ Wv, __bf16* __restrict__ Wp)
{
    const int t    = blockIdx.x * 256 + threadIdx.x;   // 0..24575
    const int lane = t & 63;
    const int pg   = t >> 6;                           // 0..383
    const int s    = pg & 3;
    const int c    = (pg >> 2) & 31;
    const int p    = pg >> 7;
    const int m16  = lane & 15;
    const int quad = lane >> 4;

    const float* W = (p == 0) ? Wq : (p == 1) ? Wk : Wv;
    const float* src = W + (size_t)(c * 32 + quad * 8) * 64 + s * 16 + m16;
    bf16x8 frag;
    #pragma unroll
    for (int j = 0; j < 8; ++j) frag[j] = (__bf16)src[(size_t)j * 64];
    *(bf16x8*)(Wp + (size_t)pg * 512 + lane * 8) = frag;
}

// Kernel 1: fused QKV projection, K-split across waves.
// grid = 1024 blocks (16 rows each), block = 256 = 4 waves.
// Per kstep: 1 ds_read A-frag, then ALL 12 Wp fragments loaded into a
// register batch (12 outstanding loads), sched_barrier, then 12 MFMAs.
__global__ __launch_bounds__(256) void qkv_fused(
    const float* __restrict__ x,     // [16384][1024] fp32
    const __bf16* __restrict__ Wp,   // [384][512] fragment-packed bf16
    const float* __restrict__ bq, const float* __restrict__ bk,
    const float* __restrict__ bv,
    __bf16* __restrict__ Q, __bf16* __restrict__ K, __bf16* __restrict__ Vt)
{
    __shared__ alignas(16) unsigned char Smem[36864];  // Xs (33792) ∪ Red (36864)

    const int rt   = blockIdx.x;                  // 0..1023
    const int wave = threadIdx.x >> 6;            // K-slice owner
    const int lane = threadIdx.x & 63;
    const int m16  = lane & 15;
    const int quad = lane >> 4;
    const int row0 = rt * 16;

    __bf16* Xs = (__bf16*)(Smem + wave * 8448);   // 16 rows x 264 (pad 8)

    // ---- Phase 1: stage x-slice (16 rows x 256 cols), fp32 -> bf16 ----
    {
        const float* xsrc = x + (size_t)row0 * 1024 + wave * 256;
        const int sr = lane >> 5;                 // 0..1
        const int sc = (lane & 31) * 8;           // 0..248
        #pragma unroll
        for (int i = 0; i < 8; ++i) {
            const int r = i * 2 + sr;
            f32x4 v0 = *(const f32x4*)(xsrc + (size_t)r * 1024 + sc);
            f32x4 v1 = *(const f32x4*)(xsrc + (size_t)r * 1024 + sc + 4);
            bf16x8 w;
            #pragma unroll
            for (int e = 0; e < 4; ++e) { w[e] = (__bf16)v0[e]; w[4 + e] = (__bf16)v1[e]; }
            *(bf16x8*)&Xs[r * 264 + sc] = w;
        }
    }
    __builtin_amdgcn_wave_barrier();   // pin DS write->read order (wave-local)

    // ---- Phase 2: K-loop with batched Wp loads ----
    f32x4 acc[3][4];
    #pragma unroll
    for (int p = 0; p < 3; ++p)
        #pragma unroll
        for (int s = 0; s < 4; ++s) acc[p][s] = {0.f, 0.f, 0.f, 0.f};

    for (int k0 = 0; k0 < 256; k0 += 32) {
        bf16x8 a = *(const bf16x8*)&Xs[m16 * 264 + k0 + quad * 8];
        const int cbase = wave * 8 + (k0 >> 5);

        bf16x8 bf[12];                 // all 12 loads in flight before any use
        #pragma unroll
        for (int ps = 0; ps < 12; ++ps) {
            const int p = ps >> 2, s = ps & 3;
            bf[ps] = *(const bf16x8*)(Wp +
                ((size_t)((p * 32 + cbase) * 4 + s) << 9) + lane * 8);
        }
        __builtin_amdgcn_sched_barrier(0);   // keep loads above, MFMAs below

        #pragma unroll
        for (int ps = 0; ps < 12; ++ps)
            acc[ps >> 2][ps & 3] =
                __builtin_amdgcn_mfma_f32_16x16x32_bf16(a, bf[ps], acc[ps >> 2][ps & 3], 0, 0, 0);
    }

    // ---- Phase 3: cross-wave reduce (Red overlays dead Xs) + epilogue ----
    f32x4* Red = (f32x4*)Smem;                    // [3][12][64]
    __syncthreads();                              // all Xs reads done
    if (wave != 0) {
        #pragma unroll
        for (int p = 0; p < 3; ++p)
            #pragma unroll
            for (int s = 0; s < 4; ++s)
                Red[((wave - 1) * 12 + p * 4 + s) * 64 + lane] = acc[p][s];
    }
    __syncthreads();
    if (wave != 0) return;

    #pragma unroll
    for (int p = 0; p < 3; ++p)
        #pragma unroll
        for (int s = 0; s < 4; ++s) {
            f32x4 sum = acc[p][s];
            #pragma unroll
            for (int w = 0; w < 3; ++w) {
                f32x4 v = Red[(w * 12 + p * 4 + s) * 64 + lane];
                #pragma unroll
                for (int e = 0; e < 4; ++e) sum[e] += v[e];
            }
            acc[p][s] = sum;
        }

    // Q epilogue (p=0)
    #pragma unroll
    for (int s = 0; s < 4; ++s) {
        const int h = s * 16 + m16;
        const float bia = bq[h];
        #pragma unroll
        for (int r = 0; r < 4; ++r)
            Q[(size_t)(row0 + quad * 4 + r) * 64 + h] = (__bf16)(acc[0][s][r] + bia);
    }
    // K epilogue (p=1)
    #pragma unroll
    for (int s = 0; s < 4; ++s) {
        const int h = s * 16 + m16;
        const float bia = bk[h];
        #pragma unroll
        for (int r = 0; r < 4; ++r)
            K[(size_t)(row0 + quad * 4 + r) * 64 + h] = (__bf16)(acc[1][s][r] + bia);
    }
    // V epilogue (p=2), transposed Vt[b][h][t]
    {
        const int bidx = row0 >> 11;
        const int t0   = (row0 & 2047) + quad * 4;
        #pragma unroll
        for (int s = 0; s < 4; ++s) {
            const int h = s * 16 + m16;
            const float bia = bv[h];
            bf16x4 pack;
            #pragma unroll
            for (int r = 0; r < 4; ++r) pack[r] = (__bf16)(acc[2][s][r] + bia);
            *(bf16x4*)(Vt + (size_t)bidx * (HS_ * T_) + (size_t)h * T_ + t0) = pack;
        }
    }
}

// Kernel 2: split-K causal attention partials, S^T scheme.
// grid = (8 key-slots, 32 q-tiles, 8 batches), block = 256 (4 waves x 16 q).
__global__ __launch_bounds__(256) void attn_partial(
    const __bf16* __restrict__ Q,   // [8][2048][64]
    const __bf16* __restrict__ K,   // [8][2048][64]
    const __bf16* __restrict__ Vt,  // [8][64][2048]
    float* __restrict__ Opart,      // [8*32*8][64][64]
    float* __restrict__ Ml)         // [8*32*8][64][2]
{
    __shared__ alignas(16) __bf16 Klds[8 * 512];   // 8 frag-groups x 1KB
    __shared__ alignas(16) __bf16 Vlds[8 * 512];

    const int z  = blockIdx.x;      // key slot 0..7
    const int qt = blockIdx.y;      // q tile 0..31
    const int b  = blockIdx.z;      // batch
    if (z > qt) return;             // uniform exit, before any barrier

    const int tid  = threadIdx.x;
    const int wave = tid >> 6;
    const int lane = tid & 63;
    const int m16  = lane & 15;
    const int quad = lane >> 4;

    const __bf16* Qb = Q  + (size_t)b * T_ * HS_;
    const __bf16* Kb = K  + (size_t)b * T_ * HS_;
    const __bf16* Vb = Vt + (size_t)b * HS_ * T_;

    const int q0   = qt * 64 + wave * 16;
    const int qrow = q0 + m16;                    // this lane's q row

    bf16x8 qb0 = *(const bf16x8*)(Qb + (size_t)qrow * 64 + quad * 8);
    bf16x8 qb1 = *(const bf16x8*)(Qb + (size_t)qrow * 64 + 32 + quad * 8);

    f32x4 o[4];                                   // O^T: h=hs*16+quad*4+r, q=m16
    #pragma unroll
    for (int hs = 0; hs < 4; ++hs) o[hs] = {0.f, 0.f, 0.f, 0.f};
    float m_run = -1e30f, l_run = 0.f;

    for (int jt = z; jt <= qt; jt += 8) {         // uniform trip count in block
        const int j0 = jt * 64;

        // stage K,V tile frag-packed; coalesced 16B/thread x2
        #pragma unroll
        for (int i = 0; i < 2; ++i) {
            const int p    = i * 256 + tid;       // piece 0..511
            const int trow = p >> 3;              // 0..63
            const int tcol = p & 7;               // 8-elem chunk
            bf16x8 kv = *(const bf16x8*)(Kb + (size_t)(j0 + trow) * 64 + tcol * 8);
            const int snb = ((trow >> 5) << 1) | ((trow >> 2) & 1);
            const int mk  = (((trow >> 3) & 3) << 2) | (trow & 3);
            *(bf16x8*)&Klds[((((snb << 1) | (tcol >> 2)) << 6) + (tcol & 3) * 16 + mk) * 8] = kv;
            bf16x8 vv = *(const bf16x8*)(Vb + (size_t)trow * T_ + j0 + tcol * 8);
            *(bf16x8*)&Vlds[(((((trow >> 4) << 1) | (tcol >> 2)) << 6) + (tcol & 3) * 16 + (trow & 15)) * 8] = vv;
        }
        __syncthreads();

        // S^T = K.Q^T
        f32x4 s[4];
        #pragma unroll
        for (int snb = 0; snb < 4; ++snb) s[snb] = {0.f, 0.f, 0.f, 0.f};
        #pragma unroll
        for (int snb = 0; snb < 4; ++snb) {
            bf16x8 ka0 = *(const bf16x8*)&Klds[((snb * 2 + 0) * 64 + lane) * 8];
            bf16x8 ka1 = *(const bf16x8*)&Klds[((snb * 2 + 1) * 64 + lane) * 8];
            s[snb] = __builtin_amdgcn_mfma_f32_16x16x32_bf16(ka0, qb0, s[snb], 0, 0, 0);
            s[snb] = __builtin_amdgcn_mfma_f32_16x16x32_bf16(ka1, qb1, s[snb], 0, 0, 0);
        }

        // softmax: lane holds 16 keys of q=qrow; 2+2 shuffles total
        float mx = -1e30f;
        #pragma unroll
        for (int snb = 0; snb < 4; ++snb) {
            const int kbase = j0 + ((snb >> 1) << 5) + (quad << 3) + ((snb & 1) << 2);
            #pragma unroll
            for (int r = 0; r < 4; ++r) {
                float v = s[snb][r] * 0.125f;             // 1/sqrt(64)
                v = (kbase + r <= qrow) ? v : -1e30f;     // causal (phys key)
                s[snb][r] = v;
                mx = fmaxf(mx, v);
            }
        }
        mx = fmaxf(mx, __shfl_xor(mx, 16));
        mx = fmaxf(mx, __shfl_xor(mx, 32));

        const float newm  = fmaxf(m_run, mx);
        const float alpha = __expf(m_run - newm);
        m_run = newm;

        float rs = 0.f;
        #pragma unroll
        for (int snb = 0; snb < 4; ++snb)
            #pragma unroll
            for (int r = 0; r < 4; ++r) {
                float pv = __expf(s[snb][r] - newm);
                s[snb][r] = pv;
                rs += pv;
            }
        rs += __shfl_xor(rs, 16);
        rs += __shfl_xor(rs, 32);
        l_run = l_run * alpha + rs;

        #pragma unroll
        for (int hs = 0; hs < 4; ++hs)
            #pragma unroll
            for (int r = 0; r < 4; ++r) o[hs][r] *= alpha;

        // P^T (registers) -> PV B-operand directly
        bf16x8 pb0, pb1;
        #pragma unroll
        for (int r = 0; r < 4; ++r) {
            pb0[r]     = (__bf16)s[0][r];
            pb0[4 + r] = (__bf16)s[1][r];
            pb1[r]     = (__bf16)s[2][r];
            pb1[4 + r] = (__bf16)s[3][r];
        }

        // O^T += Vt . P^T
        #pragma unroll
        for (int hs = 0; hs < 4; ++hs) {
            bf16x8 va0 = *(const bf16x8*)&Vlds[((hs * 2 + 0) * 64 + lane) * 8];
            bf16x8 va1 = *(const bf16x8*)&Vlds[((hs * 2 + 1) * 64 + lane) * 8];
            o[hs] = __builtin_amdgcn_mfma_f32_16x16x32_bf16(va0, pb0, o[hs], 0, 0, 0);
            o[hs] = __builtin_amdgcn_mfma_f32_16x16x32_bf16(va1, pb1, o[hs], 0, 0, 0);
        }
        __syncthreads();   // LDS reads done before next tile's staging
    }

    // epilogue: Opart[q][h] fp32 (16B stores), Ml per q
    const int slot = (b * 32 + qt) * 8 + z;
    float* Op = Opart + (size_t)slot * 4096;
    #pragma unroll
    for (int hs = 0; hs < 4; ++hs)
        *(f32x4*)(Op + (size_t)(wave * 16 + m16) * 64 + hs * 16 + quad * 4) = o[hs];
    if (quad == 0) {
        Ml[(size_t)slot * 128 + (wave * 16 + m16) * 2 + 0] = m_run;
        Ml[(size_t)slot * 128 + (wave * 16 + m16) * 2 + 1] = l_run;
    }
}

// Kernel 3: merge the <=8 slot-partials per q-tile (log-sum-exp weighting).
__global__ __launch_bounds__(256) void attn_merge(
    const float* __restrict__ Opart, const float* __restrict__ Ml,
    float* __restrict__ O)
{
    const int qt = blockIdx.x;
    const int b  = blockIdx.y;
    const int tid = threadIdx.x;
    const int row = tid >> 2;
    const int colblk = tid & 3;
    const int nc = (qt + 1 < 8) ? qt + 1 : 8;
    const int slotBase = (b * 32 + qt) * 8;

    f32x4 acc[4];
    #pragma unroll
    for (int j = 0; j < 4; ++j) acc[j] = {0.f, 0.f, 0.f, 0.f};
    float M = -1e30f, den = 0.f;

    for (int c = 0; c < nc; ++c) {
        const float* mlp = Ml + (size_t)(slotBase + c) * 128 + row * 2;
        const float mc = mlp[0];
        const float lc = mlp[1];
        const float newM  = fmaxf(M, mc);
        const float alpha = __expf(M - newM);
        const float w     = __expf(mc - newM);
        M = newM;

        const float* op = Opart + (size_t)(slotBase + c) * 4096 + row * 64 + colblk * 16;
        #pragma unroll
        for (int j = 0; j < 4; ++j) {
            f32x4 v = *(const f32x4*)(op + j * 4);
            #pragma unroll
            for (int e = 0; e < 4; ++e) acc[j][e] = acc[j][e] * alpha + w * v[e];
        }
        den = den * alpha + w * lc;
    }

    const float inv = 1.f / den;
    float* out = O + ((size_t)b * T_ + qt * 64 + row) * 64 + colblk * 16;
    #pragma unroll
    for (int j = 0; j < 4; ++j) {
        f32x4 v;
        #pragma unroll
        for (int e = 0; e < 4; ++e) v[e] = acc[j][e] * inv;
        *(f32x4*)(out + j * 4) = v;
    }
}

// ---------------------------------------------------------------------------
extern "C" void kernel_launch(void* const* d_in, const int* in_sizes, int n_in,
                              void* d_out, int out_size, void* d_ws, size_t ws_size,
                              hipStream_t stream)
{
    const float* x  = (const float*)d_in[0];
    const float* Wq = (const float*)d_in[1];
    const float* bq = (const float*)d_in[2];
    const float* Wk = (const float*)d_in[3];
    const float* bk = (const float*)d_in[4];
    const float* Wv = (const float*)d_in[5];
    const float* bv = (const float*)d_in[6];
    float* out = (float*)d_out;

    __bf16* Wp = (__bf16*)d_ws;              // 384*512 bf16         = 0.4 MB
    __bf16* Q  = Wp + 384 * 512;             // 8*2048*64 bf16       = 2 MB
    __bf16* K  = Q  + (size_t)B_ * T_ * HS_;
    __bf16* Vt = K  + (size_t)B_ * T_ * HS_; // transposed [b][h][t]
    float* Opart = (float*)(Vt + (size_t)B_ * T_ * HS_);  // 2048*4096 f32 = 33.6 MB
    float* Ml    = Opart + (size_t)2048 * 4096;           // 2048*128  f32 =  1 MB

    pack_w<<<96, 256, 0, stream>>>(Wq, Wk, Wv, Wp);
    qkv_fused<<<1024, 256, 0, stream>>>(x, Wp, bq, bk, bv, Q, K, Vt);
    attn_partial<<<dim3(8, 32, 8), 256, 0, stream>>>(Q, K, Vt, Opart, Ml);
    attn_merge<<<dim3(32, 8), 256, 0, stream>>>(Opart, Ml, out);
}